// Round 6
// baseline (74258.789 us; speedup 1.0000x reference)
//
#include <hip/hip_runtime.h>
#include <hip/hip_bf16.h>

#define DEV __device__ __forceinline__

DEV float4 ld4(const float* p) { return *reinterpret_cast<const float4*>(p); }
DEV float sigmoidf_(float x) { return 1.f / (1.f + expf(-x)); }

DEV void fma8(float (&a)[8], float xv, float4 wa, float4 wb) {
  a[0] = fmaf(xv, wa.x, a[0]); a[1] = fmaf(xv, wa.y, a[1]);
  a[2] = fmaf(xv, wa.z, a[2]); a[3] = fmaf(xv, wa.w, a[3]);
  a[4] = fmaf(xv, wb.x, a[4]); a[5] = fmaf(xv, wb.y, a[5]);
  a[6] = fmaf(xv, wb.z, a[6]); a[7] = fmaf(xv, wb.w, a[7]);
}
DEV void fma4(float (&a)[4], float xv, float4 wa) {
  a[0] = fmaf(xv, wa.x, a[0]); a[1] = fmaf(xv, wa.y, a[1]);
  a[2] = fmaf(xv, wa.z, a[2]); a[3] = fmaf(xv, wa.w, a[3]);
}
DEV float4 wfma4(float4 a, float w, float4 r) {
  a.x = __fadd_rn(a.x, __fmul_rn(w, r.x));
  a.y = __fadd_rn(a.y, __fmul_rn(w, r.y));
  a.z = __fadd_rn(a.z, __fmul_rn(w, r.z));
  a.w = __fadd_rn(a.w, __fmul_rn(w, r.w));
  return a;
}

// ---------------- CSR build (deterministic, stable) ----------------

__global__ void count_kernel(const int* __restrict__ dst, int* __restrict__ cnt, int E) {
  int e = blockIdx.x * blockDim.x + threadIdx.x;
  if (e < E) atomicAdd(&cnt[dst[e]], 1);  // counts order-independent -> deterministic
}

__global__ __launch_bounds__(256) void blockreduce_kernel(const int* __restrict__ cnt,
                                                          int* __restrict__ bsum, int n) {
  int i = blockIdx.x * 256 + threadIdx.x;
  int v = (i < n) ? cnt[i] : 0;
#pragma unroll
  for (int d = 1; d < 64; d <<= 1) v += __shfl_xor(v, d, 64);
  __shared__ int sh[4];
  if ((threadIdx.x & 63) == 0) sh[threadIdx.x >> 6] = v;
  __syncthreads();
  if (threadIdx.x == 0) bsum[blockIdx.x] = sh[0] + sh[1] + sh[2] + sh[3];
}

__global__ __launch_bounds__(256) void scanb_kernel(const int* __restrict__ bsum,
                                                    int* __restrict__ boff, int nb) {
  __shared__ int sh[256];
  int t = threadIdx.x;
  int orig = (t < nb) ? bsum[t] : 0;
  int v = orig;
  sh[t] = v;
  __syncthreads();
  for (int d = 1; d < 256; d <<= 1) {
    int a = (t >= d) ? sh[t - d] : 0;
    __syncthreads();
    v += a;
    sh[t] = v;
    __syncthreads();
  }
  if (t < nb) boff[t] = v - orig;  // exclusive
}

__global__ __launch_bounds__(256) void blockscan_kernel(
    const int* __restrict__ cnt, const int* __restrict__ boff,
    int* __restrict__ off, int* __restrict__ cur, int n, int total) {
  __shared__ int sh[256];
  int b = blockIdx.x, t = threadIdx.x;
  int i = b * 256 + t;
  int orig = (i < n) ? cnt[i] : 0;
  int v = orig;
  sh[t] = v;
  __syncthreads();
  for (int d = 1; d < 256; d <<= 1) {
    int a = (t >= d) ? sh[t - d] : 0;
    __syncthreads();
    v += a;
    sh[t] = v;
    __syncthreads();
  }
  int excl = v - orig + boff[b];
  if (i < n) { off[i] = excl; cur[i] = excl; }
  if (i == n - 1) off[n] = total;
}

__global__ void scatter_kernel(const int* __restrict__ dstI, int* __restrict__ cur,
                               int* __restrict__ eidx, int E) {
  int e = blockIdx.x * blockDim.x + threadIdx.x;
  if (e < E) {
    int p = atomicAdd(&cur[dstI[e]], 1);
    eidx[p] = e;
  }
}

// per-node wave rank-sort by edge index -> deterministic stable order
// (ascending edge index == np.add.at accumulation order)
__global__ __launch_bounds__(256) void sortseg_kernel(
    const int* __restrict__ off, int* __restrict__ eidx,
    const int* __restrict__ srcI, const float* __restrict__ ew,
    int* __restrict__ csrc, float* __restrict__ cw, int n) {
  int node = blockIdx.x * 4 + (threadIdx.x >> 6);
  int lane = threadIdx.x & 63;
  if (node >= n) return;
  int s = off[node], e = off[node + 1];
  int deg = e - s;
  if (deg <= 0) return;
  if (deg <= 64) {
    int v = (lane < deg) ? eidx[s + lane] : 2147483647;
    int rank = 0;
    for (int m = 0; m < 64; ++m) {
      int u = __shfl(v, m, 64);
      rank += (u < v) ? 1 : 0;  // edge indices unique
    }
    if (lane < deg) {
      csrc[s + rank] = srcI[v];
      cw[s + rank]   = ew[v];
    }
  } else if (lane == 0) {
    for (int i = s + 1; i < e; ++i) {
      int key = eidx[i]; int j = i - 1;
      while (j >= s && eidx[j] > key) { eidx[j + 1] = eidx[j]; --j; }
      eidx[j + 1] = key;
    }
    for (int i = s; i < e; ++i) {
      int v = eidx[i];
      csrc[i] = srcI[v];
      cw[i]   = ew[v];
    }
  }
}

// layer-0 x aggregation for all timesteps (graph is time-invariant)
__global__ __launch_bounds__(256) void aggx0_kernel(
    const int* __restrict__ off, const int* __restrict__ csrc, const float* __restrict__ cw,
    const float* __restrict__ x, float* __restrict__ ax, int n) {
  int node = blockIdx.x * 8 + (threadIdx.x >> 5);
  int lane = threadIdx.x & 31;
  if (node >= n || lane >= 24) return;
  float a = 0.f;
  int s = off[node], e = off[node + 1];
#pragma unroll 1
  for (int i = s; i < e; ++i)
    a = __fadd_rn(a, __fmul_rn(cw[i], x[(size_t)csrc[i] * 24 + lane]));
  ax[(size_t)node * 24 + lane] = a;
}

// ---------------- fused agg + gates ----------------
// Phase A: 16-lane group per node gathers h (and o1t for L1) into LDS.
//   Strict ascending edge order, __fmul_rn/__fadd_rn -> bit-identical chains.
//   #pragma unroll 1: prevent software-pipelining register balloon (round-5
//   lesson: pipelined dynamic gather + matmul in one kernel -> 256 VGPR + spills).
// Phase B: zr = sigmoid([aggx, aggh] @ Wg + bg); z -> zb, r*h -> rhb.

template <int LAYER>
__global__ __launch_bounds__(256, 3) void fgates_kernel(
    const int* __restrict__ off, const int* __restrict__ csrc, const float* __restrict__ cw,
    const float* __restrict__ hb,     // h table: gather source + r*h in epilogue
    const float* __restrict__ xsrc,   // L0: aggx0 + 2t (stride 24); L1: o1t table (gather)
    float* __restrict__ aggx1,        // L1: store aggregated x for fcand; L0: unused
    const float* __restrict__ Wg, const float* __restrict__ bg,
    float* __restrict__ zb, float* __restrict__ rhb, int n) {
  __shared__ float sh_h[16][68];
  __shared__ float sh_x[16][68];
  const int tid = threadIdx.x;
  const int nl = tid >> 4;
  const int node = blockIdx.x * 16 + nl;
  const int g4 = (tid & 15) * 4;

  if (node < n) {
    const int s = off[node], e = off[node + 1];
    if constexpr (LAYER == 1) {
      // separate loops per table: round-4-proven low-pressure shape;
      // per-table accumulation chain identical to the fused-loop version
      float4 ax = make_float4(0.f, 0.f, 0.f, 0.f);
#pragma unroll 1
      for (int i = s; i < e; ++i)
        ax = wfma4(ax, cw[i], ld4(xsrc + (size_t)csrc[i] * 64 + g4));
      *reinterpret_cast<float4*>(&sh_x[nl][g4]) = ax;
      *reinterpret_cast<float4*>(aggx1 + (size_t)node * 64 + g4) = ax;
    }
    float4 ah = make_float4(0.f, 0.f, 0.f, 0.f);
#pragma unroll 1
    for (int i = s; i < e; ++i)
      ah = wfma4(ah, cw[i], ld4(hb + (size_t)csrc[i] * 64 + g4));
    *reinterpret_cast<float4*>(&sh_h[nl][g4]) = ah;
  }
  __syncthreads();
  if (node >= n) return;

  constexpr int KX = (LAYER == 0) ? 2 : 64;
  const int j0 = (tid & 15) * 8;
  float a[8];
#pragma unroll
  for (int i = 0; i < 8; ++i) a[i] = 0.f;

  // h part first (K = 64) -- same order as previous rounds
  {
    const float* Wh = Wg + KX * 128;
    for (int k = 0; k < 64; k += 4) {
      float4 f = ld4(&sh_h[nl][k]);
#pragma unroll
      for (int kk = 0; kk < 4; ++kk) {
        const float* wr = Wh + (k + kk) * 128 + j0;
        fma8(a, ((const float*)&f)[kk], ld4(wr), ld4(wr + 4));
      }
    }
  }
  // x part
  if constexpr (LAYER == 0) {
    float x0 = xsrc[(size_t)node * 24];
    float x1 = xsrc[(size_t)node * 24 + 1];
#pragma unroll
    for (int k = 0; k < 2; ++k) {
      const float* wr = Wg + k * 128 + j0;
      fma8(a, k ? x1 : x0, ld4(wr), ld4(wr + 4));
    }
  } else {
    for (int k = 0; k < 64; k += 4) {
      float4 f = ld4(&sh_x[nl][k]);
#pragma unroll
      for (int kk = 0; kk < 4; ++kk) {
        const float* wr = Wg + (k + kk) * 128 + j0;
        fma8(a, ((const float*)&f)[kk], ld4(wr), ld4(wr + 4));
      }
    }
  }
#pragma unroll
  for (int i = 0; i < 8; ++i) {
    int j = j0 + i;
    float sg = sigmoidf_(a[i] + bg[j]);
    if (j < 64) {
      zb[(size_t)node * 64 + j] = sg;
    } else {
      int jj = j - 64;
      rhb[(size_t)node * 64 + jj] = __fmul_rn(sg, hb[(size_t)node * 64 + jj]);
    }
  }
}

// ---------------- fused agg + candidate + GRU update ----------------
// Phase A: gather r*h into LDS (bit-identical chain, unroll 1).
// Phase B: cand = tanh([aggx, aggrh] @ Wc + bc); h = z*h + (1-z)*cand.

template <int LAYER>
__global__ __launch_bounds__(256, 3) void fcand_kernel(
    const int* __restrict__ off, const int* __restrict__ csrc, const float* __restrict__ cw,
    const float* __restrict__ rhb,
    const float* __restrict__ xsrc,   // L0: aggx0 + 2t (stride 24); L1: aggx1 (stride 64)
    const float* __restrict__ Wc, const float* __restrict__ bc,
    const float* __restrict__ zb, float* __restrict__ hb,
    float* __restrict__ outp, int ostride, int n) {
  __shared__ float sh_rh[16][68];
  const int tid = threadIdx.x;
  const int nl = tid >> 4;
  const int node = blockIdx.x * 16 + nl;
  const int g4 = (tid & 15) * 4;

  if (node < n) {
    const int s = off[node], e = off[node + 1];
    float4 ar = make_float4(0.f, 0.f, 0.f, 0.f);
#pragma unroll 1
    for (int i = s; i < e; ++i)
      ar = wfma4(ar, cw[i], ld4(rhb + (size_t)csrc[i] * 64 + g4));
    *reinterpret_cast<float4*>(&sh_rh[nl][g4]) = ar;
  }
  __syncthreads();
  if (node >= n) return;

  constexpr int KX = (LAYER == 0) ? 2 : 64;
  const int j0 = (tid & 15) * 4;
  float a[4];
#pragma unroll
  for (int i = 0; i < 4; ++i) a[i] = 0.f;

  // h part first (K = 64)
  {
    const float* Wh = Wc + KX * 64;
    for (int k = 0; k < 64; k += 4) {
      float4 f = ld4(&sh_rh[nl][k]);
#pragma unroll
      for (int kk = 0; kk < 4; ++kk)
        fma4(a, ((const float*)&f)[kk], ld4(Wh + (k + kk) * 64 + j0));
    }
  }
  // x part
  if constexpr (LAYER == 0) {
    float x0 = xsrc[(size_t)node * 24];
    float x1 = xsrc[(size_t)node * 24 + 1];
#pragma unroll
    for (int k = 0; k < 2; ++k)
      fma4(a, k ? x1 : x0, ld4(Wc + k * 64 + j0));
  } else {
    const float* gx = xsrc + (size_t)node * 64;
    for (int k = 0; k < 64; k += 4) {
      float4 f = ld4(gx + k);
#pragma unroll
      for (int kk = 0; kk < 4; ++kk)
        fma4(a, ((const float*)&f)[kk], ld4(Wc + (k + kk) * 64 + j0));
    }
  }
#pragma unroll
  for (int i = 0; i < 4; ++i) {
    int j = j0 + i;
    float c = tanhf(a[i] + bc[j]);
    float z = zb[(size_t)node * 64 + j];
    float h = hb[(size_t)node * 64 + j];
    float hn = __fadd_rn(__fmul_rn(z, h), __fmul_rn(1.f - z, c));  // match np rounding
    hb[(size_t)node * 64 + j] = hn;
    outp[(size_t)node * ostride + j] = hn;
  }
}

// ---------------- launch ----------------

extern "C" void kernel_launch(void* const* d_in, const int* in_sizes, int n_in,
                              void* d_out, int out_size, void* d_ws, size_t ws_size,
                              hipStream_t stream) {
  const float* x   = (const float*)d_in[0];
  const float* h0  = (const float*)d_in[1];
  const int*   ei  = (const int*)  d_in[2];
  const float* ew  = (const float*)d_in[3];
  const float* Wg0 = (const float*)d_in[4];
  const float* bg0 = (const float*)d_in[5];
  const float* Wc0 = (const float*)d_in[6];
  const float* bc0 = (const float*)d_in[7];
  const float* Wg1 = (const float*)d_in[8];
  const float* bg1 = (const float*)d_in[9];
  const float* Wc1 = (const float*)d_in[10];
  const float* bc1 = (const float*)d_in[11];

  const int N = in_sizes[0] / 24;  // T*F = 24
  const int E = in_sizes[2] / 2;
  const int NH = N * 64;
  const int NB = (N + 255) / 256;

  float* h1   = (float*)d_out;      // N*64
  float* h2   = h1 + NH;            // N*64
  float* out2 = h2 + NH;            // N*T*64, layout [n][t][j]

  char* w = (char*)d_ws;
  auto alloc = [&](size_t bytes) {
    char* p = w;
    w += (bytes + 255) & ~(size_t)255;
    return p;
  };
  int*   cnt   = (int*)  alloc((size_t)N * 4);
  int*   off   = (int*)  alloc((size_t)(N + 1) * 4);
  int*   cur   = (int*)  alloc((size_t)N * 4);
  int*   csrc  = (int*)  alloc((size_t)E * 4);
  float* cw    = (float*)alloc((size_t)E * 4);
  int*   bsum  = (int*)  alloc(256 * 4);
  int*   boff  = (int*)  alloc(256 * 4);
  float* aggx0 = (float*)alloc((size_t)N * 24 * 4);
  float* aggx1 = (float*)alloc((size_t)NH * 4);
  float* zb    = (float*)alloc((size_t)NH * 4);
  float* rhb   = (float*)alloc((size_t)NH * 4);
  float* o1t   = (float*)alloc((size_t)NH * 4);
  int*   eidx  = (int*)aggx1;  // alias: aggx1 first written inside the t-loop

  const int* srcI = ei;
  const int* dstI = ei + E;

  hipMemcpyAsync(d_out, h0, (size_t)2 * NH * 4, hipMemcpyDeviceToDevice, stream);

  // deterministic & stable CSR: sorted by (dst, original edge index)
  hipMemsetAsync(cnt, 0, (size_t)N * 4, stream);
  count_kernel<<<(E + 255) / 256, 256, 0, stream>>>(dstI, cnt, E);
  blockreduce_kernel<<<NB, 256, 0, stream>>>(cnt, bsum, N);
  scanb_kernel<<<1, 256, 0, stream>>>(bsum, boff, NB);
  blockscan_kernel<<<NB, 256, 0, stream>>>(cnt, boff, off, cur, N, E);
  scatter_kernel<<<(E + 255) / 256, 256, 0, stream>>>(dstI, cur, eidx, E);
  sortseg_kernel<<<(N + 3) / 4, 256, 0, stream>>>(off, eidx, srcI, ew, csrc, cw, N);

  aggx0_kernel<<<(N + 7) / 8, 256, 0, stream>>>(off, csrc, cw, x, aggx0, N);

  const int gf = (N + 15) / 16;  // fused kernels: 16 nodes/block

  for (int t = 0; t < 12; ++t) {
    // ---- layer 0 ----
    fgates_kernel<0><<<gf, 256, 0, stream>>>(off, csrc, cw, h1, aggx0 + 2 * t, nullptr,
                                             Wg0, bg0, zb, rhb, N);
    fcand_kernel<0><<<gf, 256, 0, stream>>>(off, csrc, cw, rhb, aggx0 + 2 * t,
                                            Wc0, bc0, zb, h1, o1t, 64, N);
    // ---- layer 1 ----
    fgates_kernel<1><<<gf, 256, 0, stream>>>(off, csrc, cw, h2, o1t, aggx1,
                                             Wg1, bg1, zb, rhb, N);
    fcand_kernel<1><<<gf, 256, 0, stream>>>(off, csrc, cw, rhb, aggx1,
                                            Wc1, bc1, zb, h2,
                                            out2 + (size_t)t * 64, 12 * 64, N);
  }
}

// Round 7
// 5753.156 us; speedup vs baseline: 12.9075x; 12.9075x over previous
//
#include <hip/hip_runtime.h>
#include <hip/hip_bf16.h>

#define DEV __device__ __forceinline__

DEV float4 ld4(const float* p) { return *reinterpret_cast<const float4*>(p); }
DEV float sigmoidf_(float x) { return 1.f / (1.f + expf(-x)); }

DEV void fma8(float (&a)[8], float xv, float4 wa, float4 wb) {
  a[0] = fmaf(xv, wa.x, a[0]); a[1] = fmaf(xv, wa.y, a[1]);
  a[2] = fmaf(xv, wa.z, a[2]); a[3] = fmaf(xv, wa.w, a[3]);
  a[4] = fmaf(xv, wb.x, a[4]); a[5] = fmaf(xv, wb.y, a[5]);
  a[6] = fmaf(xv, wb.z, a[6]); a[7] = fmaf(xv, wb.w, a[7]);
}
DEV float4 wfma4(float4 a, float w, float4 r) {
  a.x = __fadd_rn(a.x, __fmul_rn(w, r.x));
  a.y = __fadd_rn(a.y, __fmul_rn(w, r.y));
  a.z = __fadd_rn(a.z, __fmul_rn(w, r.z));
  a.w = __fadd_rn(a.w, __fmul_rn(w, r.w));
  return a;
}

// ---------------- CSR build (deterministic, stable) ----------------

__global__ void count_kernel(const int* __restrict__ dst, int* __restrict__ cnt, int E) {
  int e = blockIdx.x * blockDim.x + threadIdx.x;
  if (e < E) atomicAdd(&cnt[dst[e]], 1);  // counts order-independent -> deterministic
}

__global__ __launch_bounds__(256) void blockreduce_kernel(const int* __restrict__ cnt,
                                                          int* __restrict__ bsum, int n) {
  int i = blockIdx.x * 256 + threadIdx.x;
  int v = (i < n) ? cnt[i] : 0;
#pragma unroll
  for (int d = 1; d < 64; d <<= 1) v += __shfl_xor(v, d, 64);
  __shared__ int sh[4];
  if ((threadIdx.x & 63) == 0) sh[threadIdx.x >> 6] = v;
  __syncthreads();
  if (threadIdx.x == 0) bsum[blockIdx.x] = sh[0] + sh[1] + sh[2] + sh[3];
}

__global__ __launch_bounds__(256) void scanb_kernel(const int* __restrict__ bsum,
                                                    int* __restrict__ boff, int nb) {
  __shared__ int sh[256];
  int t = threadIdx.x;
  int orig = (t < nb) ? bsum[t] : 0;
  int v = orig;
  sh[t] = v;
  __syncthreads();
  for (int d = 1; d < 256; d <<= 1) {
    int a = (t >= d) ? sh[t - d] : 0;
    __syncthreads();
    v += a;
    sh[t] = v;
    __syncthreads();
  }
  if (t < nb) boff[t] = v - orig;  // exclusive
}

__global__ __launch_bounds__(256) void blockscan_kernel(
    const int* __restrict__ cnt, const int* __restrict__ boff,
    int* __restrict__ off, int* __restrict__ cur, int n, int total) {
  __shared__ int sh[256];
  int b = blockIdx.x, t = threadIdx.x;
  int i = b * 256 + t;
  int orig = (i < n) ? cnt[i] : 0;
  int v = orig;
  sh[t] = v;
  __syncthreads();
  for (int d = 1; d < 256; d <<= 1) {
    int a = (t >= d) ? sh[t - d] : 0;
    __syncthreads();
    v += a;
    sh[t] = v;
    __syncthreads();
  }
  int excl = v - orig + boff[b];
  if (i < n) { off[i] = excl; cur[i] = excl; }
  if (i == n - 1) off[n] = total;
}

__global__ void scatter_kernel(const int* __restrict__ dstI, int* __restrict__ cur,
                               int* __restrict__ eidx, int E) {
  int e = blockIdx.x * blockDim.x + threadIdx.x;
  if (e < E) {
    int p = atomicAdd(&cur[dstI[e]], 1);
    eidx[p] = e;
  }
}

// per-node wave rank-sort by edge index -> deterministic stable order
// (ascending edge index == np.add.at accumulation order).
// Writes the packed (src, weight) stream: one 8B record per edge.
__global__ __launch_bounds__(256) void sortseg_kernel(
    const int* __restrict__ off, int* __restrict__ eidx,
    const int* __restrict__ srcI, const float* __restrict__ ew,
    int2* __restrict__ cse, int n) {
  int node = blockIdx.x * 4 + (threadIdx.x >> 6);
  int lane = threadIdx.x & 63;
  if (node >= n) return;
  int s = off[node], e = off[node + 1];
  int deg = e - s;
  if (deg <= 0) return;
  if (deg <= 64) {
    int v = (lane < deg) ? eidx[s + lane] : 2147483647;
    int rank = 0;
    for (int m = 0; m < 64; ++m) {
      int u = __shfl(v, m, 64);
      rank += (u < v) ? 1 : 0;  // edge indices unique
    }
    if (lane < deg)
      cse[s + rank] = make_int2(srcI[v], __float_as_int(ew[v]));
  } else if (lane == 0) {
    for (int i = s + 1; i < e; ++i) {
      int key = eidx[i]; int j = i - 1;
      while (j >= s && eidx[j] > key) { eidx[j + 1] = eidx[j]; --j; }
      eidx[j + 1] = key;
    }
    for (int i = s; i < e; ++i) {
      int v = eidx[i];
      cse[i] = make_int2(srcI[v], __float_as_int(ew[v]));
    }
  }
}

// layer-0 x aggregation for all timesteps (graph is time-invariant)
__global__ __launch_bounds__(256) void aggx0_kernel(
    const int* __restrict__ off, const int2* __restrict__ cse,
    const float* __restrict__ x, float* __restrict__ ax, int n) {
  int node = blockIdx.x * 8 + (threadIdx.x >> 5);
  int lane = threadIdx.x & 31;
  if (node >= n || lane >= 24) return;
  float a = 0.f;
  int s = off[node], e = off[node + 1];
  for (int i = s; i < e; ++i) {
    int2 p = cse[i];
    a = __fadd_rn(a, __fmul_rn(__int_as_float(p.y), x[(size_t)p.x * 24 + lane]));
  }
  ax[(size_t)node * 24 + lane] = a;
}

// ---------------- aggregation (pull, CSR) ----------------
// 16-lane group per node, float4 per lane => one full 256B row per edge-step.
// Strict ascending edge order; __fmul_rn/__fadd_rn match np rounding.

__global__ __launch_bounds__(256) void agg1_kernel(
    const int* __restrict__ off, const int2* __restrict__ cse,
    const float* __restrict__ f0, float* __restrict__ o0, int n) {
  const int node = blockIdx.x * 16 + (threadIdx.x >> 4);  // 16-lane group per node
  const int g4   = (threadIdx.x & 15) * 4;                // feature quad
  if (node >= n) return;
  int s = off[node], e = off[node + 1];
  float4 acc = make_float4(0.f, 0.f, 0.f, 0.f);
  for (int i = s; i < e; ++i) {
    int2 p = cse[i];
    acc = wfma4(acc, __int_as_float(p.y), ld4(f0 + (size_t)p.x * 64 + g4));
  }
  *reinterpret_cast<float4*>(o0 + (size_t)node * 64 + g4) = acc;
}

// fused double gather (two feature tables, shared index stream)
__global__ __launch_bounds__(256) void agg2_kernel(
    const int* __restrict__ off, const int2* __restrict__ cse,
    const float* __restrict__ f0, float* __restrict__ o0,
    const float* __restrict__ f1, float* __restrict__ o1, int n) {
  const int node = blockIdx.x * 16 + (threadIdx.x >> 4);
  const int g4   = (threadIdx.x & 15) * 4;
  if (node >= n) return;
  int s = off[node], e = off[node + 1];
  float4 a0 = make_float4(0.f, 0.f, 0.f, 0.f);
  float4 a1 = a0;
  for (int i = s; i < e; ++i) {
    int2 p = cse[i];
    float w = __int_as_float(p.y);
    size_t ro = (size_t)p.x * 64 + g4;
    a0 = wfma4(a0, w, ld4(f0 + ro));
    a1 = wfma4(a1, w, ld4(f1 + ro));
  }
  *reinterpret_cast<float4*>(o0 + (size_t)node * 64 + g4) = a0;
  *reinterpret_cast<float4*>(o1 + (size_t)node * 64 + g4) = a1;
}

// ---------------- gates: zr = sigmoid([aggx, aggh] @ Wg + bg); z, rh = z, r*h ----------------

template <int KX>
__global__ __launch_bounds__(256) void gates_kernel(
    const float* __restrict__ aggx, int sx,
    const float* __restrict__ aggh,
    const float* __restrict__ Wg, const float* __restrict__ bg,
    const float* __restrict__ hb, float* __restrict__ zb, float* __restrict__ rhb, int n) {
  const int t = threadIdx.x;
  const int j0 = (t & 15) * 8;
  const int r0 = blockIdx.x * 32 + (t >> 4) * 2;
  if (r0 >= n) return;
  const int r1 = r0 + 1;
  const bool v1 = r1 < n;
  float a0[8], a1[8];
#pragma unroll
  for (int i = 0; i < 8; ++i) { a0[i] = 0.f; a1[i] = 0.f; }

  {
    const float* Wh = Wg + KX * 128;
    const float* f0p = aggh + (size_t)r0 * 64;
    const float* f1p = aggh + (size_t)(v1 ? r1 : r0) * 64;
    for (int k = 0; k < 64; k += 4) {
      float4 f0 = ld4(f0p + k);
      float4 f1 = ld4(f1p + k);
#pragma unroll
      for (int kk = 0; kk < 4; ++kk) {
        const float* wr = Wh + (k + kk) * 128 + j0;
        float4 wa = ld4(wr), wb = ld4(wr + 4);
        fma8(a0, ((const float*)&f0)[kk], wa, wb);
        fma8(a1, ((const float*)&f1)[kk], wa, wb);
      }
    }
  }
  if constexpr (KX == 2) {
    float x00 = aggx[(size_t)r0 * sx], x01 = aggx[(size_t)r0 * sx + 1];
    float x10 = v1 ? aggx[(size_t)r1 * sx] : 0.f;
    float x11 = v1 ? aggx[(size_t)r1 * sx + 1] : 0.f;
#pragma unroll
    for (int k = 0; k < 2; ++k) {
      const float* wr = Wg + k * 128 + j0;
      float4 wa = ld4(wr), wb = ld4(wr + 4);
      fma8(a0, k ? x01 : x00, wa, wb);
      fma8(a1, k ? x11 : x10, wa, wb);
    }
  } else {
    const float* g0p = aggx + (size_t)r0 * sx;
    const float* g1p = aggx + (size_t)(v1 ? r1 : r0) * sx;
    for (int k = 0; k < KX; k += 4) {
      float4 f0 = ld4(g0p + k);
      float4 f1 = ld4(g1p + k);
#pragma unroll
      for (int kk = 0; kk < 4; ++kk) {
        const float* wr = Wg + (k + kk) * 128 + j0;
        float4 wa = ld4(wr), wb = ld4(wr + 4);
        fma8(a0, ((const float*)&f0)[kk], wa, wb);
        fma8(a1, ((const float*)&f1)[kk], wa, wb);
      }
    }
  }
#pragma unroll
  for (int i = 0; i < 8; ++i) {
    int j = j0 + i;
    float b = bg[j];
    float s0 = sigmoidf_(a0[i] + b);
    float s1 = sigmoidf_(a1[i] + b);
    if (j < 64) {
      zb[(size_t)r0 * 64 + j] = s0;
      if (v1) zb[(size_t)r1 * 64 + j] = s1;
    } else {
      int jj = j - 64;
      rhb[(size_t)r0 * 64 + jj] = __fmul_rn(s0, hb[(size_t)r0 * 64 + jj]);
      if (v1) rhb[(size_t)r1 * 64 + jj] = __fmul_rn(s1, hb[(size_t)r1 * 64 + jj]);
    }
  }
}

// ---------------- candidate + GRU update ----------------

template <int KX>
__global__ __launch_bounds__(256) void cand_kernel(
    const float* __restrict__ aggx, int sx,
    const float* __restrict__ aggrh,
    const float* __restrict__ Wc, const float* __restrict__ bc,
    const float* __restrict__ zb, float* __restrict__ hb,
    float* __restrict__ outp, int ostride, int n) {
  const int t = threadIdx.x;
  const int j0 = (t & 7) * 8;
  const int r0 = blockIdx.x * 64 + (t >> 3) * 2;
  if (r0 >= n) return;
  const int r1 = r0 + 1;
  const bool v1 = r1 < n;
  float a0[8], a1[8];
#pragma unroll
  for (int i = 0; i < 8; ++i) { a0[i] = 0.f; a1[i] = 0.f; }

  {
    const float* Wh = Wc + KX * 64;
    const float* f0p = aggrh + (size_t)r0 * 64;
    const float* f1p = aggrh + (size_t)(v1 ? r1 : r0) * 64;
    for (int k = 0; k < 64; k += 4) {
      float4 f0 = ld4(f0p + k);
      float4 f1 = ld4(f1p + k);
#pragma unroll
      for (int kk = 0; kk < 4; ++kk) {
        const float* wr = Wh + (k + kk) * 64 + j0;
        float4 wa = ld4(wr), wb = ld4(wr + 4);
        fma8(a0, ((const float*)&f0)[kk], wa, wb);
        fma8(a1, ((const float*)&f1)[kk], wa, wb);
      }
    }
  }
  if constexpr (KX == 2) {
    float x00 = aggx[(size_t)r0 * sx], x01 = aggx[(size_t)r0 * sx + 1];
    float x10 = v1 ? aggx[(size_t)r1 * sx] : 0.f;
    float x11 = v1 ? aggx[(size_t)r1 * sx + 1] : 0.f;
#pragma unroll
    for (int k = 0; k < 2; ++k) {
      const float* wr = Wc + k * 64 + j0;
      float4 wa = ld4(wr), wb = ld4(wr + 4);
      fma8(a0, k ? x01 : x00, wa, wb);
      fma8(a1, k ? x11 : x10, wa, wb);
    }
  } else {
    const float* g0p = aggx + (size_t)r0 * sx;
    const float* g1p = aggx + (size_t)(v1 ? r1 : r0) * sx;
    for (int k = 0; k < KX; k += 4) {
      float4 f0 = ld4(g0p + k);
      float4 f1 = ld4(g1p + k);
#pragma unroll
      for (int kk = 0; kk < 4; ++kk) {
        const float* wr = Wc + (k + kk) * 64 + j0;
        float4 wa = ld4(wr), wb = ld4(wr + 4);
        fma8(a0, ((const float*)&f0)[kk], wa, wb);
        fma8(a1, ((const float*)&f1)[kk], wa, wb);
      }
    }
  }
#pragma unroll
  for (int i = 0; i < 8; ++i) {
    int j = j0 + i;
    float b = bc[j];
    float c0 = tanhf(a0[i] + b);
    float c1 = tanhf(a1[i] + b);
    {
      float z = zb[(size_t)r0 * 64 + j];
      float h = hb[(size_t)r0 * 64 + j];
      float hn = __fadd_rn(__fmul_rn(z, h), __fmul_rn(1.f - z, c0));
      hb[(size_t)r0 * 64 + j] = hn;
      outp[(size_t)r0 * ostride + j] = hn;
    }
    if (v1) {
      float z = zb[(size_t)r1 * 64 + j];
      float h = hb[(size_t)r1 * 64 + j];
      float hn = __fadd_rn(__fmul_rn(z, h), __fmul_rn(1.f - z, c1));
      hb[(size_t)r1 * 64 + j] = hn;
      outp[(size_t)r1 * ostride + j] = hn;
    }
  }
}

// ---------------- launch ----------------

extern "C" void kernel_launch(void* const* d_in, const int* in_sizes, int n_in,
                              void* d_out, int out_size, void* d_ws, size_t ws_size,
                              hipStream_t stream) {
  const float* x   = (const float*)d_in[0];
  const float* h0  = (const float*)d_in[1];
  const int*   ei  = (const int*)  d_in[2];
  const float* ew  = (const float*)d_in[3];
  const float* Wg0 = (const float*)d_in[4];
  const float* bg0 = (const float*)d_in[5];
  const float* Wc0 = (const float*)d_in[6];
  const float* bc0 = (const float*)d_in[7];
  const float* Wg1 = (const float*)d_in[8];
  const float* bg1 = (const float*)d_in[9];
  const float* Wc1 = (const float*)d_in[10];
  const float* bc1 = (const float*)d_in[11];

  const int N = in_sizes[0] / 24;  // T*F = 24
  const int E = in_sizes[2] / 2;
  const int NH = N * 64;
  const int NB = (N + 255) / 256;

  float* h1   = (float*)d_out;      // N*64
  float* h2   = h1 + NH;            // N*64
  float* out2 = h2 + NH;            // N*T*64, layout [n][t][j]

  char* w = (char*)d_ws;
  auto alloc = [&](size_t bytes) {
    char* p = w;
    w += (bytes + 255) & ~(size_t)255;
    return p;
  };
  int*   cnt   = (int*)  alloc((size_t)N * 4);
  int*   off   = (int*)  alloc((size_t)(N + 1) * 4);
  int*   cur   = (int*)  alloc((size_t)N * 4);
  int2*  cse   = (int2*) alloc((size_t)E * 8);   // packed (src, weight)
  int*   bsum  = (int*)  alloc(256 * 4);
  int*   boff  = (int*)  alloc(256 * 4);
  float* aggx0 = (float*)alloc((size_t)N * 24 * 4);
  float* aggx1 = (float*)alloc((size_t)NH * 4);
  float* aggh  = (float*)alloc((size_t)NH * 4);
  float* aggrh = (float*)alloc((size_t)NH * 4);
  float* zb    = (float*)alloc((size_t)NH * 4);
  float* rhb   = (float*)alloc((size_t)NH * 4);
  float* o1t   = (float*)alloc((size_t)NH * 4);
  int*   eidx  = (int*)aggx1;  // alias: aggx1 first written inside the t-loop

  const int* srcI = ei;
  const int* dstI = ei + E;

  hipMemcpyAsync(d_out, h0, (size_t)2 * NH * 4, hipMemcpyDeviceToDevice, stream);

  // deterministic & stable CSR: sorted by (dst, original edge index)
  hipMemsetAsync(cnt, 0, (size_t)N * 4, stream);
  count_kernel<<<(E + 255) / 256, 256, 0, stream>>>(dstI, cnt, E);
  blockreduce_kernel<<<NB, 256, 0, stream>>>(cnt, bsum, N);
  scanb_kernel<<<1, 256, 0, stream>>>(bsum, boff, NB);
  blockscan_kernel<<<NB, 256, 0, stream>>>(cnt, boff, off, cur, N, E);
  scatter_kernel<<<(E + 255) / 256, 256, 0, stream>>>(dstI, cur, eidx, E);
  sortseg_kernel<<<(N + 3) / 4, 256, 0, stream>>>(off, eidx, srcI, ew, cse, N);

  // layer-0 x aggregation, all timesteps at once (graph is time-invariant)
  aggx0_kernel<<<(N + 7) / 8, 256, 0, stream>>>(off, cse, x, aggx0, N);

  const int gagg = (N + 15) / 16;  // 16 nodes/block (16-lane group per node)
  const int ggat = (N + 31) / 32;
  const int gcan = (N + 63) / 64;

  for (int t = 0; t < 12; ++t) {
    // ---- layer 0 ----
    agg1_kernel<<<gagg, 256, 0, stream>>>(off, cse, h1, aggh, N);
    gates_kernel<2><<<ggat, 256, 0, stream>>>(aggx0 + 2 * t, 24, aggh, Wg0, bg0, h1, zb, rhb, N);
    agg1_kernel<<<gagg, 256, 0, stream>>>(off, cse, rhb, aggrh, N);
    cand_kernel<2><<<gcan, 256, 0, stream>>>(aggx0 + 2 * t, 24, aggrh, Wc0, bc0, zb, h1, o1t, 64, N);
    // ---- layer 1 ----
    agg2_kernel<<<gagg, 256, 0, stream>>>(off, cse, o1t, aggx1, h2, aggh, N);
    gates_kernel<64><<<ggat, 256, 0, stream>>>(aggx1, 64, aggh, Wg1, bg1, h2, zb, rhb, N);
    agg1_kernel<<<gagg, 256, 0, stream>>>(off, cse, rhb, aggrh, N);
    cand_kernel<64><<<gcan, 256, 0, stream>>>(aggx1, 64, aggrh, Wc1, bc1, zb, h2,
                                              out2 + (size_t)t * 64, 12 * 64, N);
  }
}

// Round 8
// 5062.427 us; speedup vs baseline: 14.6686x; 1.1364x over previous
//
#include <hip/hip_runtime.h>
#include <hip/hip_bf16.h>

#define DEV __device__ __forceinline__

DEV float4 ld4(const float* p) { return *reinterpret_cast<const float4*>(p); }
DEV float sigmoidf_(float x) { return 1.f / (1.f + expf(-x)); }

DEV void fma8(float (&a)[8], float xv, float4 wa, float4 wb) {
  a[0] = fmaf(xv, wa.x, a[0]); a[1] = fmaf(xv, wa.y, a[1]);
  a[2] = fmaf(xv, wa.z, a[2]); a[3] = fmaf(xv, wa.w, a[3]);
  a[4] = fmaf(xv, wb.x, a[4]); a[5] = fmaf(xv, wb.y, a[5]);
  a[6] = fmaf(xv, wb.z, a[6]); a[7] = fmaf(xv, wb.w, a[7]);
}
DEV void fma4(float (&a)[4], float xv, float4 wa) {
  a[0] = fmaf(xv, wa.x, a[0]); a[1] = fmaf(xv, wa.y, a[1]);
  a[2] = fmaf(xv, wa.z, a[2]); a[3] = fmaf(xv, wa.w, a[3]);
}
DEV float4 wfma4(float4 a, float w, float4 r) {
  a.x = __fadd_rn(a.x, __fmul_rn(w, r.x));
  a.y = __fadd_rn(a.y, __fmul_rn(w, r.y));
  a.z = __fadd_rn(a.z, __fmul_rn(w, r.z));
  a.w = __fadd_rn(a.w, __fmul_rn(w, r.w));
  return a;
}

// ---------------- CSR build (deterministic, stable) ----------------

__global__ void count_kernel(const int* __restrict__ dst, int* __restrict__ cnt, int E) {
  int e = blockIdx.x * blockDim.x + threadIdx.x;
  if (e < E) atomicAdd(&cnt[dst[e]], 1);  // counts order-independent -> deterministic
}

__global__ __launch_bounds__(256) void blockreduce_kernel(const int* __restrict__ cnt,
                                                          int* __restrict__ bsum, int n) {
  int i = blockIdx.x * 256 + threadIdx.x;
  int v = (i < n) ? cnt[i] : 0;
#pragma unroll
  for (int d = 1; d < 64; d <<= 1) v += __shfl_xor(v, d, 64);
  __shared__ int sh[4];
  if ((threadIdx.x & 63) == 0) sh[threadIdx.x >> 6] = v;
  __syncthreads();
  if (threadIdx.x == 0) bsum[blockIdx.x] = sh[0] + sh[1] + sh[2] + sh[3];
}

__global__ __launch_bounds__(256) void scanb_kernel(const int* __restrict__ bsum,
                                                    int* __restrict__ boff, int nb) {
  __shared__ int sh[256];
  int t = threadIdx.x;
  int orig = (t < nb) ? bsum[t] : 0;
  int v = orig;
  sh[t] = v;
  __syncthreads();
  for (int d = 1; d < 256; d <<= 1) {
    int a = (t >= d) ? sh[t - d] : 0;
    __syncthreads();
    v += a;
    sh[t] = v;
    __syncthreads();
  }
  if (t < nb) boff[t] = v - orig;  // exclusive
}

__global__ __launch_bounds__(256) void blockscan_kernel(
    const int* __restrict__ cnt, const int* __restrict__ boff,
    int* __restrict__ off, int* __restrict__ cur, int n, int total) {
  __shared__ int sh[256];
  int b = blockIdx.x, t = threadIdx.x;
  int i = b * 256 + t;
  int orig = (i < n) ? cnt[i] : 0;
  int v = orig;
  sh[t] = v;
  __syncthreads();
  for (int d = 1; d < 256; d <<= 1) {
    int a = (t >= d) ? sh[t - d] : 0;
    __syncthreads();
    v += a;
    sh[t] = v;
    __syncthreads();
  }
  int excl = v - orig + boff[b];
  if (i < n) { off[i] = excl; cur[i] = excl; }
  if (i == n - 1) off[n] = total;
}

__global__ void scatter_kernel(const int* __restrict__ dstI, int* __restrict__ cur,
                               int* __restrict__ eidx, int E) {
  int e = blockIdx.x * blockDim.x + threadIdx.x;
  if (e < E) {
    int p = atomicAdd(&cur[dstI[e]], 1);
    eidx[p] = e;
  }
}

// per-node wave rank-sort by edge index -> deterministic stable order
// (ascending edge index == np.add.at accumulation order).
__global__ __launch_bounds__(256) void sortseg_kernel(
    const int* __restrict__ off, int* __restrict__ eidx,
    const int* __restrict__ srcI, const float* __restrict__ ew,
    int2* __restrict__ cse, int n) {
  int node = blockIdx.x * 4 + (threadIdx.x >> 6);
  int lane = threadIdx.x & 63;
  if (node >= n) return;
  int s = off[node], e = off[node + 1];
  int deg = e - s;
  if (deg <= 0) return;
  if (deg <= 64) {
    int v = (lane < deg) ? eidx[s + lane] : 2147483647;
    int rank = 0;
    for (int m = 0; m < 64; ++m) {
      int u = __shfl(v, m, 64);
      rank += (u < v) ? 1 : 0;  // edge indices unique
    }
    if (lane < deg)
      cse[s + rank] = make_int2(srcI[v], __float_as_int(ew[v]));
  } else if (lane == 0) {
    for (int i = s + 1; i < e; ++i) {
      int key = eidx[i]; int j = i - 1;
      while (j >= s && eidx[j] > key) { eidx[j + 1] = eidx[j]; --j; }
      eidx[j + 1] = key;
    }
    for (int i = s; i < e; ++i) {
      int v = eidx[i];
      cse[i] = make_int2(srcI[v], __float_as_int(ew[v]));
    }
  }
}

// layer-0 x aggregation for all timesteps (graph is time-invariant)
__global__ __launch_bounds__(256) void aggx0_kernel(
    const int* __restrict__ off, const int2* __restrict__ cse,
    const float* __restrict__ x, float* __restrict__ ax, int n) {
  int node = blockIdx.x * 8 + (threadIdx.x >> 5);
  int lane = threadIdx.x & 31;
  if (node >= n || lane >= 24) return;
  float a = 0.f;
  int s = off[node], e = off[node + 1];
  int i = s;
  for (; i + 3 < e; i += 4) {
    int2 p0 = cse[i], p1 = cse[i + 1], p2 = cse[i + 2], p3 = cse[i + 3];
    float r0 = x[(size_t)p0.x * 24 + lane];
    float r1 = x[(size_t)p1.x * 24 + lane];
    float r2 = x[(size_t)p2.x * 24 + lane];
    float r3 = x[(size_t)p3.x * 24 + lane];
    a = __fadd_rn(a, __fmul_rn(__int_as_float(p0.y), r0));
    a = __fadd_rn(a, __fmul_rn(__int_as_float(p1.y), r1));
    a = __fadd_rn(a, __fmul_rn(__int_as_float(p2.y), r2));
    a = __fadd_rn(a, __fmul_rn(__int_as_float(p3.y), r3));
  }
  for (; i < e; ++i) {
    int2 p = cse[i];
    a = __fadd_rn(a, __fmul_rn(__int_as_float(p.y), x[(size_t)p.x * 24 + lane]));
  }
  ax[(size_t)node * 24 + lane] = a;
}

// ---------------- aggregation (pull, CSR) ----------------
// 16-lane group per node, float4 per lane => one full 256B row per edge.
// 4-deep explicit prefetch: 4 independent row-loads in flight, then strict
// ascending-edge in-order accumulation (bit-identical to the scalar chain).

__global__ __launch_bounds__(256) void agg1_kernel(
    const int* __restrict__ off, const int2* __restrict__ cse,
    const float* __restrict__ f0, float* __restrict__ o0, int n) {
  const int node = blockIdx.x * 16 + (threadIdx.x >> 4);  // 16-lane group per node
  const int g4   = (threadIdx.x & 15) * 4;                // feature quad
  if (node >= n) return;
  int s = off[node], e = off[node + 1];
  float4 acc = make_float4(0.f, 0.f, 0.f, 0.f);
  int i = s;
  for (; i + 3 < e; i += 4) {
    int2 p0 = cse[i], p1 = cse[i + 1], p2 = cse[i + 2], p3 = cse[i + 3];
    float4 r0 = ld4(f0 + (size_t)p0.x * 64 + g4);
    float4 r1 = ld4(f0 + (size_t)p1.x * 64 + g4);
    float4 r2 = ld4(f0 + (size_t)p2.x * 64 + g4);
    float4 r3 = ld4(f0 + (size_t)p3.x * 64 + g4);
    acc = wfma4(acc, __int_as_float(p0.y), r0);
    acc = wfma4(acc, __int_as_float(p1.y), r1);
    acc = wfma4(acc, __int_as_float(p2.y), r2);
    acc = wfma4(acc, __int_as_float(p3.y), r3);
  }
  for (; i < e; ++i) {
    int2 p = cse[i];
    acc = wfma4(acc, __int_as_float(p.y), ld4(f0 + (size_t)p.x * 64 + g4));
  }
  *reinterpret_cast<float4*>(o0 + (size_t)node * 64 + g4) = acc;
}

// fused double gather (two feature tables, shared index stream), 2-deep prefetch
__global__ __launch_bounds__(256) void agg2_kernel(
    const int* __restrict__ off, const int2* __restrict__ cse,
    const float* __restrict__ f0, float* __restrict__ o0,
    const float* __restrict__ f1, float* __restrict__ o1, int n) {
  const int node = blockIdx.x * 16 + (threadIdx.x >> 4);
  const int g4   = (threadIdx.x & 15) * 4;
  if (node >= n) return;
  int s = off[node], e = off[node + 1];
  float4 a0 = make_float4(0.f, 0.f, 0.f, 0.f);
  float4 a1 = a0;
  int i = s;
  for (; i + 1 < e; i += 2) {
    int2 p0 = cse[i], p1 = cse[i + 1];
    size_t ro0 = (size_t)p0.x * 64 + g4;
    size_t ro1 = (size_t)p1.x * 64 + g4;
    float4 x0 = ld4(f0 + ro0);
    float4 h0v = ld4(f1 + ro0);
    float4 x1 = ld4(f0 + ro1);
    float4 h1v = ld4(f1 + ro1);
    float w0 = __int_as_float(p0.y), w1 = __int_as_float(p1.y);
    a0 = wfma4(a0, w0, x0);
    a1 = wfma4(a1, w0, h0v);
    a0 = wfma4(a0, w1, x1);
    a1 = wfma4(a1, w1, h1v);
  }
  for (; i < e; ++i) {
    int2 p = cse[i];
    float w = __int_as_float(p.y);
    size_t ro = (size_t)p.x * 64 + g4;
    a0 = wfma4(a0, w, ld4(f0 + ro));
    a1 = wfma4(a1, w, ld4(f1 + ro));
  }
  *reinterpret_cast<float4*>(o0 + (size_t)node * 64 + g4) = a0;
  *reinterpret_cast<float4*>(o1 + (size_t)node * 64 + g4) = a1;
}

// ---------------- gates: zr = sigmoid([aggx, aggh] @ Wg + bg) ----------------
// 4 rows/thread x 8 outs: weight loads amortized over 4 rows.
// Per-output K-order chain identical to previous rounds (h part, then x part).

template <int KX>
__global__ __launch_bounds__(256) void gates_kernel(
    const float* __restrict__ aggx, int sx,
    const float* __restrict__ aggh,
    const float* __restrict__ Wg, const float* __restrict__ bg,
    const float* __restrict__ hb, float* __restrict__ zb, float* __restrict__ rhb, int n) {
  const int t = threadIdx.x;
  const int j0 = (t & 15) * 8;
  const int rb = blockIdx.x * 64 + (t >> 4) * 4;  // 4 rows per thread
  if (rb >= n) return;
  const int nr = min(4, n - rb);
  float a[4][8];
#pragma unroll
  for (int r = 0; r < 4; ++r)
#pragma unroll
    for (int i = 0; i < 8; ++i) a[r][i] = 0.f;

  // h part first (K = 64)
  {
    const float* Wh = Wg + KX * 128;
    for (int k = 0; k < 64; k += 4) {
      float4 f[4];
#pragma unroll
      for (int r = 0; r < 4; ++r)
        f[r] = ld4(aggh + (size_t)(rb + (r < nr ? r : 0)) * 64 + k);
#pragma unroll
      for (int kk = 0; kk < 4; ++kk) {
        const float* wr = Wh + (k + kk) * 128 + j0;
        float4 wa = ld4(wr), wb = ld4(wr + 4);
#pragma unroll
        for (int r = 0; r < 4; ++r) fma8(a[r], ((const float*)&f[r])[kk], wa, wb);
      }
    }
  }
  // x part
  if constexpr (KX == 2) {
    float xv[4][2];
#pragma unroll
    for (int r = 0; r < 4; ++r) {
      size_t ro = (size_t)(rb + (r < nr ? r : 0)) * sx;
      xv[r][0] = aggx[ro]; xv[r][1] = aggx[ro + 1];
    }
#pragma unroll
    for (int k = 0; k < 2; ++k) {
      const float* wr = Wg + k * 128 + j0;
      float4 wa = ld4(wr), wb = ld4(wr + 4);
#pragma unroll
      for (int r = 0; r < 4; ++r) fma8(a[r], xv[r][k], wa, wb);
    }
  } else {
    for (int k = 0; k < KX; k += 4) {
      float4 f[4];
#pragma unroll
      for (int r = 0; r < 4; ++r)
        f[r] = ld4(aggx + (size_t)(rb + (r < nr ? r : 0)) * sx + k);
#pragma unroll
      for (int kk = 0; kk < 4; ++kk) {
        const float* wr = Wg + (k + kk) * 128 + j0;
        float4 wa = ld4(wr), wb = ld4(wr + 4);
#pragma unroll
        for (int r = 0; r < 4; ++r) fma8(a[r], ((const float*)&f[r])[kk], wa, wb);
      }
    }
  }
#pragma unroll
  for (int i = 0; i < 8; ++i) {
    int j = j0 + i;
    float b = bg[j];
#pragma unroll
    for (int r = 0; r < 4; ++r) {
      if (r < nr) {
        int row = rb + r;
        float sg = sigmoidf_(a[r][i] + b);
        if (j < 64) {
          zb[(size_t)row * 64 + j] = sg;
        } else {
          int jj = j - 64;
          rhb[(size_t)row * 64 + jj] = __fmul_rn(sg, hb[(size_t)row * 64 + jj]);
        }
      }
    }
  }
}

// ---------------- candidate + GRU update ----------------
// 4 rows/thread x 4 outs.

template <int KX>
__global__ __launch_bounds__(256) void cand_kernel(
    const float* __restrict__ aggx, int sx,
    const float* __restrict__ aggrh,
    const float* __restrict__ Wc, const float* __restrict__ bc,
    const float* __restrict__ zb, float* __restrict__ hb,
    float* __restrict__ outp, int ostride, int n) {
  const int t = threadIdx.x;
  const int j0 = (t & 15) * 4;
  const int rb = blockIdx.x * 64 + (t >> 4) * 4;
  if (rb >= n) return;
  const int nr = min(4, n - rb);
  float a[4][4];
#pragma unroll
  for (int r = 0; r < 4; ++r)
#pragma unroll
    for (int i = 0; i < 4; ++i) a[r][i] = 0.f;

  // h part first (K = 64)
  {
    const float* Wh = Wc + KX * 64;
    for (int k = 0; k < 64; k += 4) {
      float4 f[4];
#pragma unroll
      for (int r = 0; r < 4; ++r)
        f[r] = ld4(aggrh + (size_t)(rb + (r < nr ? r : 0)) * 64 + k);
#pragma unroll
      for (int kk = 0; kk < 4; ++kk) {
        float4 wa = ld4(Wh + (k + kk) * 64 + j0);
#pragma unroll
        for (int r = 0; r < 4; ++r) fma4(a[r], ((const float*)&f[r])[kk], wa);
      }
    }
  }
  // x part
  if constexpr (KX == 2) {
    float xv[4][2];
#pragma unroll
    for (int r = 0; r < 4; ++r) {
      size_t ro = (size_t)(rb + (r < nr ? r : 0)) * sx;
      xv[r][0] = aggx[ro]; xv[r][1] = aggx[ro + 1];
    }
#pragma unroll
    for (int k = 0; k < 2; ++k) {
      float4 wa = ld4(Wc + k * 64 + j0);
#pragma unroll
      for (int r = 0; r < 4; ++r) fma4(a[r], xv[r][k], wa);
    }
  } else {
    for (int k = 0; k < KX; k += 4) {
      float4 f[4];
#pragma unroll
      for (int r = 0; r < 4; ++r)
        f[r] = ld4(aggx + (size_t)(rb + (r < nr ? r : 0)) * sx + k);
#pragma unroll
      for (int kk = 0; kk < 4; ++kk) {
        float4 wa = ld4(Wc + (k + kk) * 64 + j0);
#pragma unroll
        for (int r = 0; r < 4; ++r) fma4(a[r], ((const float*)&f[r])[kk], wa);
      }
    }
  }
#pragma unroll
  for (int i = 0; i < 4; ++i) {
    int j = j0 + i;
    float b = bc[j];
#pragma unroll
    for (int r = 0; r < 4; ++r) {
      if (r < nr) {
        int row = rb + r;
        float c = tanhf(a[r][i] + b);
        float z = zb[(size_t)row * 64 + j];
        float h = hb[(size_t)row * 64 + j];
        float hn = __fadd_rn(__fmul_rn(z, h), __fmul_rn(1.f - z, c));  // np rounding
        hb[(size_t)row * 64 + j] = hn;
        outp[(size_t)row * ostride + j] = hn;
      }
    }
  }
}

// ---------------- launch ----------------

extern "C" void kernel_launch(void* const* d_in, const int* in_sizes, int n_in,
                              void* d_out, int out_size, void* d_ws, size_t ws_size,
                              hipStream_t stream) {
  const float* x   = (const float*)d_in[0];
  const float* h0  = (const float*)d_in[1];
  const int*   ei  = (const int*)  d_in[2];
  const float* ew  = (const float*)d_in[3];
  const float* Wg0 = (const float*)d_in[4];
  const float* bg0 = (const float*)d_in[5];
  const float* Wc0 = (const float*)d_in[6];
  const float* bc0 = (const float*)d_in[7];
  const float* Wg1 = (const float*)d_in[8];
  const float* bg1 = (const float*)d_in[9];
  const float* Wc1 = (const float*)d_in[10];
  const float* bc1 = (const float*)d_in[11];

  const int N = in_sizes[0] / 24;  // T*F = 24
  const int E = in_sizes[2] / 2;
  const int NH = N * 64;
  const int NB = (N + 255) / 256;

  float* h1   = (float*)d_out;      // N*64
  float* h2   = h1 + NH;            // N*64
  float* out2 = h2 + NH;            // N*T*64, layout [n][t][j]

  char* w = (char*)d_ws;
  auto alloc = [&](size_t bytes) {
    char* p = w;
    w += (bytes + 255) & ~(size_t)255;
    return p;
  };
  int*   cnt   = (int*)  alloc((size_t)N * 4);
  int*   off   = (int*)  alloc((size_t)(N + 1) * 4);
  int*   cur   = (int*)  alloc((size_t)N * 4);
  int2*  cse   = (int2*) alloc((size_t)E * 8);   // packed (src, weight)
  int*   bsum  = (int*)  alloc(256 * 4);
  int*   boff  = (int*)  alloc(256 * 4);
  float* aggx0 = (float*)alloc((size_t)N * 24 * 4);
  float* aggx1 = (float*)alloc((size_t)NH * 4);
  float* aggh  = (float*)alloc((size_t)NH * 4);
  float* aggrh = (float*)alloc((size_t)NH * 4);
  float* zb    = (float*)alloc((size_t)NH * 4);
  float* rhb   = (float*)alloc((size_t)NH * 4);
  float* o1t   = (float*)alloc((size_t)NH * 4);
  int*   eidx  = (int*)aggx1;  // alias: aggx1 first written inside the t-loop

  const int* srcI = ei;
  const int* dstI = ei + E;

  hipMemcpyAsync(d_out, h0, (size_t)2 * NH * 4, hipMemcpyDeviceToDevice, stream);

  // deterministic & stable CSR: sorted by (dst, original edge index)
  hipMemsetAsync(cnt, 0, (size_t)N * 4, stream);
  count_kernel<<<(E + 255) / 256, 256, 0, stream>>>(dstI, cnt, E);
  blockreduce_kernel<<<NB, 256, 0, stream>>>(cnt, bsum, N);
  scanb_kernel<<<1, 256, 0, stream>>>(bsum, boff, NB);
  blockscan_kernel<<<NB, 256, 0, stream>>>(cnt, boff, off, cur, N, E);
  scatter_kernel<<<(E + 255) / 256, 256, 0, stream>>>(dstI, cur, eidx, E);
  sortseg_kernel<<<(N + 3) / 4, 256, 0, stream>>>(off, eidx, srcI, ew, cse, N);

  // layer-0 x aggregation, all timesteps at once (graph is time-invariant)
  aggx0_kernel<<<(N + 7) / 8, 256, 0, stream>>>(off, cse, x, aggx0, N);

  const int gagg = (N + 15) / 16;  // 16 nodes/block (16-lane group per node)
  const int gmm  = (N + 63) / 64;  // matmuls: 64 rows/block, 4 rows/thread

  for (int t = 0; t < 12; ++t) {
    // ---- layer 0 ----
    agg1_kernel<<<gagg, 256, 0, stream>>>(off, cse, h1, aggh, N);
    gates_kernel<2><<<gmm, 256, 0, stream>>>(aggx0 + 2 * t, 24, aggh, Wg0, bg0, h1, zb, rhb, N);
    agg1_kernel<<<gagg, 256, 0, stream>>>(off, cse, rhb, aggrh, N);
    cand_kernel<2><<<gmm, 256, 0, stream>>>(aggx0 + 2 * t, 24, aggrh, Wc0, bc0, zb, h1, o1t, 64, N);
    // ---- layer 1 ----
    agg2_kernel<<<gagg, 256, 0, stream>>>(off, cse, o1t, aggx1, h2, aggh, N);
    gates_kernel<64><<<gmm, 256, 0, stream>>>(aggx1, 64, aggh, Wg1, bg1, h2, zb, rhb, N);
    agg1_kernel<<<gagg, 256, 0, stream>>>(off, cse, rhb, aggrh, N);
    cand_kernel<64><<<gmm, 256, 0, stream>>>(aggx1, 64, aggrh, Wc1, bc1, zb, h2,
                                             out2 + (size_t)t * 64, 12 * 64, N);
  }
}

// Round 9
// 4641.718 us; speedup vs baseline: 15.9981x; 1.0906x over previous
//
#include <hip/hip_runtime.h>
#include <hip/hip_bf16.h>

#define DEV __device__ __forceinline__

DEV float4 ld4(const float* p) { return *reinterpret_cast<const float4*>(p); }
DEV float sigmoidf_(float x) { return 1.f / (1.f + expf(-x)); }

DEV void fma8(float (&a)[8], float xv, float4 wa, float4 wb) {
  a[0] = fmaf(xv, wa.x, a[0]); a[1] = fmaf(xv, wa.y, a[1]);
  a[2] = fmaf(xv, wa.z, a[2]); a[3] = fmaf(xv, wa.w, a[3]);
  a[4] = fmaf(xv, wb.x, a[4]); a[5] = fmaf(xv, wb.y, a[5]);
  a[6] = fmaf(xv, wb.z, a[6]); a[7] = fmaf(xv, wb.w, a[7]);
}
DEV void fma4(float (&a)[4], float xv, float4 wa) {
  a[0] = fmaf(xv, wa.x, a[0]); a[1] = fmaf(xv, wa.y, a[1]);
  a[2] = fmaf(xv, wa.z, a[2]); a[3] = fmaf(xv, wa.w, a[3]);
}
DEV float4 wfma4(float4 a, float w, float4 r) {
  a.x = __fadd_rn(a.x, __fmul_rn(w, r.x));
  a.y = __fadd_rn(a.y, __fmul_rn(w, r.y));
  a.z = __fadd_rn(a.z, __fmul_rn(w, r.z));
  a.w = __fadd_rn(a.w, __fmul_rn(w, r.w));
  return a;
}

// ---------------- CSR build (deterministic, stable) ----------------

__global__ void count_kernel(const int* __restrict__ dst, int* __restrict__ cnt, int E) {
  int e = blockIdx.x * blockDim.x + threadIdx.x;
  if (e < E) atomicAdd(&cnt[dst[e]], 1);  // counts order-independent -> deterministic
}

__global__ __launch_bounds__(256) void blockreduce_kernel(const int* __restrict__ cnt,
                                                          int* __restrict__ bsum, int n) {
  int i = blockIdx.x * 256 + threadIdx.x;
  int v = (i < n) ? cnt[i] : 0;
#pragma unroll
  for (int d = 1; d < 64; d <<= 1) v += __shfl_xor(v, d, 64);
  __shared__ int sh[4];
  if ((threadIdx.x & 63) == 0) sh[threadIdx.x >> 6] = v;
  __syncthreads();
  if (threadIdx.x == 0) bsum[blockIdx.x] = sh[0] + sh[1] + sh[2] + sh[3];
}

__global__ __launch_bounds__(256) void scanb_kernel(const int* __restrict__ bsum,
                                                    int* __restrict__ boff, int nb) {
  __shared__ int sh[256];
  int t = threadIdx.x;
  int orig = (t < nb) ? bsum[t] : 0;
  int v = orig;
  sh[t] = v;
  __syncthreads();
  for (int d = 1; d < 256; d <<= 1) {
    int a = (t >= d) ? sh[t - d] : 0;
    __syncthreads();
    v += a;
    sh[t] = v;
    __syncthreads();
  }
  if (t < nb) boff[t] = v - orig;  // exclusive
}

__global__ __launch_bounds__(256) void blockscan_kernel(
    const int* __restrict__ cnt, const int* __restrict__ boff,
    int* __restrict__ off, int* __restrict__ cur, int n, int total) {
  __shared__ int sh[256];
  int b = blockIdx.x, t = threadIdx.x;
  int i = b * 256 + t;
  int orig = (i < n) ? cnt[i] : 0;
  int v = orig;
  sh[t] = v;
  __syncthreads();
  for (int d = 1; d < 256; d <<= 1) {
    int a = (t >= d) ? sh[t - d] : 0;
    __syncthreads();
    v += a;
    sh[t] = v;
    __syncthreads();
  }
  int excl = v - orig + boff[b];
  if (i < n) { off[i] = excl; cur[i] = excl; }
  if (i == n - 1) off[n] = total;
}

__global__ void scatter_kernel(const int* __restrict__ dstI, int* __restrict__ cur,
                               int* __restrict__ eidx, int E) {
  int e = blockIdx.x * blockDim.x + threadIdx.x;
  if (e < E) {
    int p = atomicAdd(&cur[dstI[e]], 1);
    eidx[p] = e;
  }
}

// per-node wave rank-sort by edge index -> deterministic stable order
// (ascending edge index == np.add.at accumulation order).
__global__ __launch_bounds__(256) void sortseg_kernel(
    const int* __restrict__ off, int* __restrict__ eidx,
    const int* __restrict__ srcI, const float* __restrict__ ew,
    int2* __restrict__ cse, int n) {
  int node = blockIdx.x * 4 + (threadIdx.x >> 6);
  int lane = threadIdx.x & 63;
  if (node >= n) return;
  int s = off[node], e = off[node + 1];
  int deg = e - s;
  if (deg <= 0) return;
  if (deg <= 64) {
    int v = (lane < deg) ? eidx[s + lane] : 2147483647;
    int rank = 0;
    for (int m = 0; m < 64; ++m) {
      int u = __shfl(v, m, 64);
      rank += (u < v) ? 1 : 0;  // edge indices unique
    }
    if (lane < deg)
      cse[s + rank] = make_int2(srcI[v], __float_as_int(ew[v]));
  } else if (lane == 0) {
    for (int i = s + 1; i < e; ++i) {
      int key = eidx[i]; int j = i - 1;
      while (j >= s && eidx[j] > key) { eidx[j + 1] = eidx[j]; --j; }
      eidx[j + 1] = key;
    }
    for (int i = s; i < e; ++i) {
      int v = eidx[i];
      cse[i] = make_int2(srcI[v], __float_as_int(ew[v]));
    }
  }
}

// layer-0 x aggregation for all timesteps (graph is time-invariant)
__global__ __launch_bounds__(256) void aggx0_kernel(
    const int* __restrict__ off, const int2* __restrict__ cse,
    const float* __restrict__ x, float* __restrict__ ax, int n) {
  int node = blockIdx.x * 8 + (threadIdx.x >> 5);
  int lane = threadIdx.x & 31;
  if (node >= n || lane >= 24) return;
  float a = 0.f;
  int s = off[node], e = off[node + 1];
  int i = s;
  for (; i + 3 < e; i += 4) {
    int2 p0 = cse[i], p1 = cse[i + 1], p2 = cse[i + 2], p3 = cse[i + 3];
    float r0 = x[(size_t)p0.x * 24 + lane];
    float r1 = x[(size_t)p1.x * 24 + lane];
    float r2 = x[(size_t)p2.x * 24 + lane];
    float r3 = x[(size_t)p3.x * 24 + lane];
    a = __fadd_rn(a, __fmul_rn(__int_as_float(p0.y), r0));
    a = __fadd_rn(a, __fmul_rn(__int_as_float(p1.y), r1));
    a = __fadd_rn(a, __fmul_rn(__int_as_float(p2.y), r2));
    a = __fadd_rn(a, __fmul_rn(__int_as_float(p3.y), r3));
  }
  for (; i < e; ++i) {
    int2 p = cse[i];
    a = __fadd_rn(a, __fmul_rn(__int_as_float(p.y), x[(size_t)p.x * 24 + lane]));
  }
  ax[(size_t)node * 24 + lane] = a;
}

// ---------------- aggregation (pull, CSR) ----------------
// 16-lane group per node, float4 per lane => one full 256B row per edge.
// cse double-buffer: next edge-quad's records load while current rows are in
// flight. Accumulation strictly ascending edge order -> bit-identical.

__global__ __launch_bounds__(256) void agg1_kernel(
    const int* __restrict__ off, const int2* __restrict__ cse,
    const float* __restrict__ f0, float* __restrict__ o0, int n) {
  const int node = blockIdx.x * 16 + (threadIdx.x >> 4);
  const int g4   = (threadIdx.x & 15) * 4;
  if (node >= n) return;
  int s = off[node], e = off[node + 1];
  float4 acc = make_float4(0.f, 0.f, 0.f, 0.f);
  int i = s;
  if (i + 3 < e) {
    int2 q0 = cse[i], q1 = cse[i + 1], q2 = cse[i + 2], q3 = cse[i + 3];
    for (; i + 7 < e; i += 4) {
      float4 r0 = ld4(f0 + (size_t)q0.x * 64 + g4);
      float4 r1 = ld4(f0 + (size_t)q1.x * 64 + g4);
      float4 r2 = ld4(f0 + (size_t)q2.x * 64 + g4);
      float4 r3 = ld4(f0 + (size_t)q3.x * 64 + g4);
      int2 m0 = cse[i + 4], m1 = cse[i + 5], m2 = cse[i + 6], m3 = cse[i + 7];
      acc = wfma4(acc, __int_as_float(q0.y), r0);
      acc = wfma4(acc, __int_as_float(q1.y), r1);
      acc = wfma4(acc, __int_as_float(q2.y), r2);
      acc = wfma4(acc, __int_as_float(q3.y), r3);
      q0 = m0; q1 = m1; q2 = m2; q3 = m3;
    }
    // drain buffered quad
    float4 r0 = ld4(f0 + (size_t)q0.x * 64 + g4);
    float4 r1 = ld4(f0 + (size_t)q1.x * 64 + g4);
    float4 r2 = ld4(f0 + (size_t)q2.x * 64 + g4);
    float4 r3 = ld4(f0 + (size_t)q3.x * 64 + g4);
    acc = wfma4(acc, __int_as_float(q0.y), r0);
    acc = wfma4(acc, __int_as_float(q1.y), r1);
    acc = wfma4(acc, __int_as_float(q2.y), r2);
    acc = wfma4(acc, __int_as_float(q3.y), r3);
    i += 4;
  }
  for (; i < e; ++i) {
    int2 p = cse[i];
    acc = wfma4(acc, __int_as_float(p.y), ld4(f0 + (size_t)p.x * 64 + g4));
  }
  *reinterpret_cast<float4*>(o0 + (size_t)node * 64 + g4) = acc;
}

// fused double gather (two tables, shared index stream), 4-edge unroll + cse dbuf
__global__ __launch_bounds__(256) void agg2_kernel(
    const int* __restrict__ off, const int2* __restrict__ cse,
    const float* __restrict__ f0, float* __restrict__ o0,
    const float* __restrict__ f1, float* __restrict__ o1, int n) {
  const int node = blockIdx.x * 16 + (threadIdx.x >> 4);
  const int g4   = (threadIdx.x & 15) * 4;
  if (node >= n) return;
  int s = off[node], e = off[node + 1];
  float4 a0 = make_float4(0.f, 0.f, 0.f, 0.f);
  float4 a1 = a0;
  int i = s;
  if (i + 3 < e) {
    int2 q0 = cse[i], q1 = cse[i + 1], q2 = cse[i + 2], q3 = cse[i + 3];
    for (; i + 7 < e; i += 4) {
      size_t o0_ = (size_t)q0.x * 64 + g4, o1_ = (size_t)q1.x * 64 + g4;
      size_t o2_ = (size_t)q2.x * 64 + g4, o3_ = (size_t)q3.x * 64 + g4;
      float4 x0 = ld4(f0 + o0_), h0 = ld4(f1 + o0_);
      float4 x1 = ld4(f0 + o1_), h1 = ld4(f1 + o1_);
      float4 x2 = ld4(f0 + o2_), h2 = ld4(f1 + o2_);
      float4 x3 = ld4(f0 + o3_), h3 = ld4(f1 + o3_);
      int2 m0 = cse[i + 4], m1 = cse[i + 5], m2 = cse[i + 6], m3 = cse[i + 7];
      float w0 = __int_as_float(q0.y), w1 = __int_as_float(q1.y);
      float w2 = __int_as_float(q2.y), w3 = __int_as_float(q3.y);
      a0 = wfma4(a0, w0, x0); a1 = wfma4(a1, w0, h0);
      a0 = wfma4(a0, w1, x1); a1 = wfma4(a1, w1, h1);
      a0 = wfma4(a0, w2, x2); a1 = wfma4(a1, w2, h2);
      a0 = wfma4(a0, w3, x3); a1 = wfma4(a1, w3, h3);
      q0 = m0; q1 = m1; q2 = m2; q3 = m3;
    }
    size_t o0_ = (size_t)q0.x * 64 + g4, o1_ = (size_t)q1.x * 64 + g4;
    size_t o2_ = (size_t)q2.x * 64 + g4, o3_ = (size_t)q3.x * 64 + g4;
    float4 x0 = ld4(f0 + o0_), h0 = ld4(f1 + o0_);
    float4 x1 = ld4(f0 + o1_), h1 = ld4(f1 + o1_);
    float4 x2 = ld4(f0 + o2_), h2 = ld4(f1 + o2_);
    float4 x3 = ld4(f0 + o3_), h3 = ld4(f1 + o3_);
    float w0 = __int_as_float(q0.y), w1 = __int_as_float(q1.y);
    float w2 = __int_as_float(q2.y), w3 = __int_as_float(q3.y);
    a0 = wfma4(a0, w0, x0); a1 = wfma4(a1, w0, h0);
    a0 = wfma4(a0, w1, x1); a1 = wfma4(a1, w1, h1);
    a0 = wfma4(a0, w2, x2); a1 = wfma4(a1, w2, h2);
    a0 = wfma4(a0, w3, x3); a1 = wfma4(a1, w3, h3);
    i += 4;
  }
  for (; i < e; ++i) {
    int2 p = cse[i];
    float w = __int_as_float(p.y);
    size_t ro = (size_t)p.x * 64 + g4;
    a0 = wfma4(a0, w, ld4(f0 + ro));
    a1 = wfma4(a1, w, ld4(f1 + ro));
  }
  *reinterpret_cast<float4*>(o0 + (size_t)node * 64 + g4) = a0;
  *reinterpret_cast<float4*>(o1 + (size_t)node * 64 + g4) = a1;
}

// ---------------- gates: zr = sigmoid([aggx, aggh] @ Wg + bg) ----------------
// Weights are block-invariant -> LDS-staged once (kills redundant L2 reads,
// which were at the L2 BW ceiling). 8 rows/thread x 8 outs, 128 rows/block.
// Per-output K-order chain identical to previous rounds (h part, then x part).

template <int KX>
__global__ __launch_bounds__(256) void gates_kernel(
    const float* __restrict__ aggx, int sx,
    const float* __restrict__ aggh,
    const float* __restrict__ Wg, const float* __restrict__ bg,
    const float* __restrict__ hb, float* __restrict__ zb, float* __restrict__ rhb, int n) {
  __shared__ float wS[(KX + 64) * 128];
  const int t = threadIdx.x;
  // cooperative weight stage (all threads)
  {
    float4* d = (float4*)wS;
    const float4* src = (const float4*)Wg;
    const int tot = (KX + 64) * 32;  // float4 count
    for (int idx = t; idx < tot; idx += 256) d[idx] = src[idx];
  }
  __syncthreads();

  const int j0 = (t & 15) * 8;
  const int rb = blockIdx.x * 128 + (t >> 4) * 8;  // 8 rows/thread
  if (rb >= n) return;
  const int nr = min(8, n - rb);
  int ro[8];
#pragma unroll
  for (int r = 0; r < 8; ++r) ro[r] = (rb + (r < nr ? r : 0)) * 64;

  float a[8][8];
#pragma unroll
  for (int r = 0; r < 8; ++r)
#pragma unroll
    for (int i = 0; i < 8; ++i) a[r][i] = 0.f;

  // h part first (K = 64)
  {
    const float* Wh = wS + KX * 128;
    for (int k = 0; k < 64; k += 4) {
      float4 f[8];
#pragma unroll
      for (int r = 0; r < 8; ++r) f[r] = ld4(aggh + ro[r] + k);
#pragma unroll
      for (int kk = 0; kk < 4; ++kk) {
        const float* wr = Wh + (k + kk) * 128 + j0;
        float4 wa = ld4(wr), wb = ld4(wr + 4);
#pragma unroll
        for (int r = 0; r < 8; ++r) fma8(a[r], ((const float*)&f[r])[kk], wa, wb);
      }
    }
  }
  // x part
  if constexpr (KX == 2) {
    float xv[8][2];
#pragma unroll
    for (int r = 0; r < 8; ++r) {
      size_t xo = (size_t)(rb + (r < nr ? r : 0)) * sx;
      xv[r][0] = aggx[xo]; xv[r][1] = aggx[xo + 1];
    }
#pragma unroll
    for (int k = 0; k < 2; ++k) {
      const float* wr = wS + k * 128 + j0;
      float4 wa = ld4(wr), wb = ld4(wr + 4);
#pragma unroll
      for (int r = 0; r < 8; ++r) fma8(a[r], xv[r][k], wa, wb);
    }
  } else {
    for (int k = 0; k < KX; k += 4) {
      float4 f[8];
#pragma unroll
      for (int r = 0; r < 8; ++r) f[r] = ld4(aggx + ro[r] + k);
#pragma unroll
      for (int kk = 0; kk < 4; ++kk) {
        const float* wr = wS + (k + kk) * 128 + j0;
        float4 wa = ld4(wr), wb = ld4(wr + 4);
#pragma unroll
        for (int r = 0; r < 8; ++r) fma8(a[r], ((const float*)&f[r])[kk], wa, wb);
      }
    }
  }
#pragma unroll
  for (int i = 0; i < 8; ++i) {
    int j = j0 + i;
    float b = bg[j];
#pragma unroll
    for (int r = 0; r < 8; ++r) {
      if (r < nr) {
        int row = rb + r;
        float sg = sigmoidf_(a[r][i] + b);
        if (j < 64) {
          zb[(size_t)row * 64 + j] = sg;
        } else {
          int jj = j - 64;
          rhb[(size_t)row * 64 + jj] = __fmul_rn(sg, hb[(size_t)row * 64 + jj]);
        }
      }
    }
  }
}

// ---------------- candidate + GRU update ----------------
// LDS-staged weights, 8 rows/thread x 4 outs, 128 rows/block.

template <int KX>
__global__ __launch_bounds__(256) void cand_kernel(
    const float* __restrict__ aggx, int sx,
    const float* __restrict__ aggrh,
    const float* __restrict__ Wc, const float* __restrict__ bc,
    const float* __restrict__ zb, float* __restrict__ hb,
    float* __restrict__ outp, int ostride, int n) {
  __shared__ float wS[(KX + 64) * 64];
  const int t = threadIdx.x;
  {
    float4* d = (float4*)wS;
    const float4* src = (const float4*)Wc;
    const int tot = (KX + 64) * 16;
    for (int idx = t; idx < tot; idx += 256) d[idx] = src[idx];
  }
  __syncthreads();

  const int j0 = (t & 15) * 4;
  const int rb = blockIdx.x * 128 + (t >> 4) * 8;
  if (rb >= n) return;
  const int nr = min(8, n - rb);
  int ro[8];
#pragma unroll
  for (int r = 0; r < 8; ++r) ro[r] = (rb + (r < nr ? r : 0)) * 64;

  float a[8][4];
#pragma unroll
  for (int r = 0; r < 8; ++r)
#pragma unroll
    for (int i = 0; i < 4; ++i) a[r][i] = 0.f;

  // h part first (K = 64)
  {
    const float* Wh = wS + KX * 64;
    for (int k = 0; k < 64; k += 4) {
      float4 f[8];
#pragma unroll
      for (int r = 0; r < 8; ++r) f[r] = ld4(aggrh + ro[r] + k);
#pragma unroll
      for (int kk = 0; kk < 4; ++kk) {
        float4 wa = ld4(Wh + (k + kk) * 64 + j0);
#pragma unroll
        for (int r = 0; r < 8; ++r) fma4(a[r], ((const float*)&f[r])[kk], wa);
      }
    }
  }
  // x part
  if constexpr (KX == 2) {
    float xv[8][2];
#pragma unroll
    for (int r = 0; r < 8; ++r) {
      size_t xo = (size_t)(rb + (r < nr ? r : 0)) * sx;
      xv[r][0] = aggx[xo]; xv[r][1] = aggx[xo + 1];
    }
#pragma unroll
    for (int k = 0; k < 2; ++k) {
      float4 wa = ld4(wS + k * 64 + j0);
#pragma unroll
      for (int r = 0; r < 8; ++r) fma4(a[r], xv[r][k], wa);
    }
  } else {
    for (int k = 0; k < KX; k += 4) {
      float4 f[8];
#pragma unroll
      for (int r = 0; r < 8; ++r) f[r] = ld4(aggx + ro[r] + k);
#pragma unroll
      for (int kk = 0; kk < 4; ++kk) {
        float4 wa = ld4(wS + (k + kk) * 64 + j0);
#pragma unroll
        for (int r = 0; r < 8; ++r) fma4(a[r], ((const float*)&f[r])[kk], wa);
      }
    }
  }
#pragma unroll
  for (int i = 0; i < 4; ++i) {
    int j = j0 + i;
    float b = bc[j];
#pragma unroll
    for (int r = 0; r < 8; ++r) {
      if (r < nr) {
        int row = rb + r;
        float c = tanhf(a[r][i] + b);
        float z = zb[(size_t)row * 64 + j];
        float h = hb[(size_t)row * 64 + j];
        float hn = __fadd_rn(__fmul_rn(z, h), __fmul_rn(1.f - z, c));  // np rounding
        hb[(size_t)row * 64 + j] = hn;
        outp[(size_t)row * ostride + j] = hn;
      }
    }
  }
}

// ---------------- launch ----------------

extern "C" void kernel_launch(void* const* d_in, const int* in_sizes, int n_in,
                              void* d_out, int out_size, void* d_ws, size_t ws_size,
                              hipStream_t stream) {
  const float* x   = (const float*)d_in[0];
  const float* h0  = (const float*)d_in[1];
  const int*   ei  = (const int*)  d_in[2];
  const float* ew  = (const float*)d_in[3];
  const float* Wg0 = (const float*)d_in[4];
  const float* bg0 = (const float*)d_in[5];
  const float* Wc0 = (const float*)d_in[6];
  const float* bc0 = (const float*)d_in[7];
  const float* Wg1 = (const float*)d_in[8];
  const float* bg1 = (const float*)d_in[9];
  const float* Wc1 = (const float*)d_in[10];
  const float* bc1 = (const float*)d_in[11];

  const int N = in_sizes[0] / 24;  // T*F = 24
  const int E = in_sizes[2] / 2;
  const int NH = N * 64;
  const int NB = (N + 255) / 256;

  float* h1   = (float*)d_out;      // N*64
  float* h2   = h1 + NH;            // N*64
  float* out2 = h2 + NH;            // N*T*64, layout [n][t][j]

  char* w = (char*)d_ws;
  auto alloc = [&](size_t bytes) {
    char* p = w;
    w += (bytes + 255) & ~(size_t)255;
    return p;
  };
  int*   cnt   = (int*)  alloc((size_t)N * 4);
  int*   off   = (int*)  alloc((size_t)(N + 1) * 4);
  int*   cur   = (int*)  alloc((size_t)N * 4);
  int2*  cse   = (int2*) alloc((size_t)E * 8);   // packed (src, weight)
  int*   bsum  = (int*)  alloc(256 * 4);
  int*   boff  = (int*)  alloc(256 * 4);
  float* aggx0 = (float*)alloc((size_t)N * 24 * 4);
  float* aggx1 = (float*)alloc((size_t)NH * 4);
  float* aggh  = (float*)alloc((size_t)NH * 4);
  float* aggrh = (float*)alloc((size_t)NH * 4);
  float* zb    = (float*)alloc((size_t)NH * 4);
  float* rhb   = (float*)alloc((size_t)NH * 4);
  float* o1t   = (float*)alloc((size_t)NH * 4);
  int*   eidx  = (int*)aggx1;  // alias: aggx1 first written inside the t-loop

  const int* srcI = ei;
  const int* dstI = ei + E;

  hipMemcpyAsync(d_out, h0, (size_t)2 * NH * 4, hipMemcpyDeviceToDevice, stream);

  // deterministic & stable CSR: sorted by (dst, original edge index)
  hipMemsetAsync(cnt, 0, (size_t)N * 4, stream);
  count_kernel<<<(E + 255) / 256, 256, 0, stream>>>(dstI, cnt, E);
  blockreduce_kernel<<<NB, 256, 0, stream>>>(cnt, bsum, N);
  scanb_kernel<<<1, 256, 0, stream>>>(bsum, boff, NB);
  blockscan_kernel<<<NB, 256, 0, stream>>>(cnt, boff, off, cur, N, E);
  scatter_kernel<<<(E + 255) / 256, 256, 0, stream>>>(dstI, cur, eidx, E);
  sortseg_kernel<<<(N + 3) / 4, 256, 0, stream>>>(off, eidx, srcI, ew, cse, N);

  // layer-0 x aggregation, all timesteps at once (graph is time-invariant)
  aggx0_kernel<<<(N + 7) / 8, 256, 0, stream>>>(off, cse, x, aggx0, N);

  const int gagg = (N + 15) / 16;   // 16 nodes/block (16-lane group per node)
  const int gmm  = (N + 127) / 128; // matmuls: 128 rows/block, 8 rows/thread

  for (int t = 0; t < 12; ++t) {
    // ---- layer 0 ----
    agg1_kernel<<<gagg, 256, 0, stream>>>(off, cse, h1, aggh, N);
    gates_kernel<2><<<gmm, 256, 0, stream>>>(aggx0 + 2 * t, 24, aggh, Wg0, bg0, h1, zb, rhb, N);
    agg1_kernel<<<gagg, 256, 0, stream>>>(off, cse, rhb, aggrh, N);
    cand_kernel<2><<<gmm, 256, 0, stream>>>(aggx0 + 2 * t, 24, aggrh, Wc0, bc0, zb, h1, o1t, 64, N);
    // ---- layer 1 ----
    agg2_kernel<<<gagg, 256, 0, stream>>>(off, cse, o1t, aggx1, h2, aggh, N);
    gates_kernel<64><<<gmm, 256, 0, stream>>>(aggx1, 64, aggh, Wg1, bg1, h2, zb, rhb, N);
    agg1_kernel<<<gagg, 256, 0, stream>>>(off, cse, rhb, aggrh, N);
    cand_kernel<64><<<gmm, 256, 0, stream>>>(aggx1, 64, aggrh, Wc1, bc1, zb, h2,
                                             out2 + (size_t)t * 64, 12 * 64, N);
  }
}